// Round 5
// baseline (417.438 us; speedup 1.0000x reference)
//
#include <hip/hip_runtime.h>
#include <hip/hip_bf16.h>
#include <cstddef>

typedef __attribute__((ext_vector_type(8))) short short8;   // 8 bf16 = 4 VGPR
typedef __attribute__((ext_vector_type(4))) float f32x4;

// cacheable 16B load
static __device__ __forceinline__ f32x4 ldg(const float* p) {
    return *(const f32x4*)p;
}
// non-temporal (streaming) 16B load: evict-first hint keeps the REUSED
// operand resident in the 4MB per-XCD L2. Theory: W re-reads (~720MB across
// m-blocks) being served from L3 at ~9TB/s is the measured 87us wall.
static __device__ __forceinline__ f32x4 ldg_nt(const float* p) {
    return __builtin_nontemporal_load((const f32x4*)p);
}

static __device__ __forceinline__ short8 pack8(f32x4 f0, f32x4 f1) {
    union { __hip_bfloat162 h[4]; short8 s; } u;
    u.h[0] = __float22bfloat162_rn(make_float2(f0.x, f0.y));
    u.h[1] = __float22bfloat162_rn(make_float2(f0.z, f0.w));
    u.h[2] = __float22bfloat162_rn(make_float2(f1.x, f1.y));
    u.h[3] = __float22bfloat162_rn(make_float2(f1.z, f1.w));
    return u.s;
}

// Non-draining workgroup barrier (lgkmcnt only; prefetch loads stay in flight).
static __device__ __forceinline__ void lds_barrier() {
    asm volatile("s_waitcnt lgkmcnt(0)" ::: "memory");
    __builtin_amdgcn_s_barrier();
    asm volatile("" ::: "memory");
}

// ===========================================================================
// Generic split-K bf16 MFMA body: adds A[m0:m0+128, kbeg:kend] @ W^T tile
// into C via atomicAdd. Tile 128(M) x 64(N), BK=32, 256 thr (4 waves, each
// 32 rows x 64 cols). N bounds-checked. C must be zero-initialized.
// Prefetch depth 2, XOR-swizzled bf16 LDS double-buffer (0 conflicts),
// ONE non-draining barrier per K-step. W loads are NON-TEMPORAL (each W row
// is read by exactly one (n,k)-block -> single-use stream); A loads cacheable
// (small activations reused by every n-block).
// Requires nsteps even and >= 2 (all call sites satisfy this).
// ===========================================================================
static __device__ __forceinline__ void sk_body(
    const float* __restrict__ A, int lda,
    const float* __restrict__ W,
    const float* __restrict__ bias, int addbias,
    float* __restrict__ C, int ldc, int N,
    int kbeg, int kend, int n0, int m0)
{
    __shared__ short As[2][128 * 32];
    __shared__ short Ws[2][64 * 32];
    const int tid  = threadIdx.x;
    const int lane = tid & 63;
    const int wave = tid >> 6;
    const int wm = wave * 32;

    f32x4 acc[2][4];
    #pragma unroll
    for (int i = 0; i < 2; ++i)
        #pragma unroll
        for (int j = 0; j < 4; ++j)
            acc[i][j] = (f32x4){0.f, 0.f, 0.f, 0.f};

    // A staging: row = tid>>1 (0..127), k-half = tid&1 -> slots 2h, 2h+1
    const int arow = tid >> 1;
    const int ah   = tid & 1;
    const int afs  = (arow >> 1) & 3;
    const float* gA = A + (size_t)(m0 + arow) * lda + kbeg + ah * 16;
    const int aoff0 = arow * 32 + (((ah * 2)     ^ afs) * 8);
    const int aoff1 = arow * 32 + (((ah * 2 + 1) ^ afs) * 8);

    // W staging: row = tid>>2 (0..63), slot = tid&3
    const int wrow  = tid >> 2;
    const int wslot = tid & 3;
    const int wvalid = (n0 + wrow) < N;
    const float* gW = W + (size_t)(n0 + wrow) * lda + kbeg + wslot * 8;
    const int woff = wrow * 32 + ((wslot ^ ((wrow >> 1) & 3)) * 8);

    // fragment read offsets
    const int frow = lane & 15;
    const int hi   = lane >> 4;
    const int fsl  = (hi ^ ((frow >> 1) & 3)) * 8;
    const int ra   = (wm + frow) * 32 + fsl;
    const int rb   = frow * 32 + fsl;

    const int nsteps = (kend - kbeg) >> 5;

    // prologue: K-tiles 0 and 1 into two register sets
    f32x4 a0_[4], a1_[4], w0_[2], w1_[2];
    #pragma unroll
    for (int q = 0; q < 4; ++q) a0_[q] = ldg(gA + q * 4);
    #pragma unroll
    for (int q = 0; q < 4; ++q) a1_[q] = ldg(gA + 32 + q * 4);
    if (wvalid) {
        w0_[0] = ldg_nt(gW);      w0_[1] = ldg_nt(gW + 4);
        w1_[0] = ldg_nt(gW + 32); w1_[1] = ldg_nt(gW + 36);
    } else {
        w0_[0] = w0_[1] = w1_[0] = w1_[1] = (f32x4){0.f, 0.f, 0.f, 0.f};
    }

    for (int s = 0; s < nsteps; s += 2) {
        // ---- even step: consume set 0 into buf 0, reload set 0 from s+2 ----
        {
            short* as = As[0]; short* ws = Ws[0];
            *(short8*)(as + aoff0) = pack8(a0_[0], a0_[1]);
            *(short8*)(as + aoff1) = pack8(a0_[2], a0_[3]);
            *(short8*)(ws + woff)  = pack8(w0_[0], w0_[1]);
            if (s + 2 < nsteps) {
                const float* nA = gA + (s + 2) * 32;
                #pragma unroll
                for (int q = 0; q < 4; ++q) a0_[q] = ldg(nA + q * 4);
                if (wvalid) {
                    const float* nW = gW + (s + 2) * 32;
                    w0_[0] = ldg_nt(nW); w0_[1] = ldg_nt(nW + 4);
                }
            }
            lds_barrier();
            short8 af[2], bf[4];
            #pragma unroll
            for (int i = 0; i < 2; ++i) af[i] = *(const short8*)(as + ra + i * 512);
            #pragma unroll
            for (int j = 0; j < 4; ++j) bf[j] = *(const short8*)(ws + rb + j * 512);
            #pragma unroll
            for (int i = 0; i < 2; ++i)
                #pragma unroll
                for (int j = 0; j < 4; ++j)
                    acc[i][j] = __builtin_amdgcn_mfma_f32_16x16x32_bf16(af[i], bf[j], acc[i][j], 0, 0, 0);
        }
        // ---- odd step: consume set 1 into buf 1, reload set 1 from s+3 ----
        {
            short* as = As[1]; short* ws = Ws[1];
            *(short8*)(as + aoff0) = pack8(a1_[0], a1_[1]);
            *(short8*)(as + aoff1) = pack8(a1_[2], a1_[3]);
            *(short8*)(ws + woff)  = pack8(w1_[0], w1_[1]);
            if (s + 3 < nsteps) {
                const float* nA = gA + (s + 3) * 32;
                #pragma unroll
                for (int q = 0; q < 4; ++q) a1_[q] = ldg(nA + q * 4);
                if (wvalid) {
                    const float* nW = gW + (s + 3) * 32;
                    w1_[0] = ldg_nt(nW); w1_[1] = ldg_nt(nW + 4);
                }
            }
            lds_barrier();
            short8 af[2], bf[4];
            #pragma unroll
            for (int i = 0; i < 2; ++i) af[i] = *(const short8*)(as + ra + i * 512);
            #pragma unroll
            for (int j = 0; j < 4; ++j) bf[j] = *(const short8*)(ws + rb + j * 512);
            #pragma unroll
            for (int i = 0; i < 2; ++i)
                #pragma unroll
                for (int j = 0; j < 4; ++j)
                    acc[i][j] = __builtin_amdgcn_mfma_f32_16x16x32_bf16(af[i], bf[j], acc[i][j], 0, 0, 0);
        }
    }

    const int cl = lane & 15;
    const int rq = hi * 4;
    #pragma unroll
    for (int j = 0; j < 4; ++j) {
        int gc = n0 + j * 16 + cl;
        if (gc >= N) continue;
        float b = addbias ? bias[gc] : 0.f;
        #pragma unroll
        for (int i = 0; i < 2; ++i) {
            int gr = m0 + wm + i * 16 + rq;
            #pragma unroll
            for (int r = 0; r < 4; ++r)
                atomicAdd(C + (size_t)(gr + r) * ldc + gc, acc[i][j][r] + b);
        }
    }
}

// generic wrapper: grid (ceil(N/64), ksplit, M/128)
__global__ __launch_bounds__(256) void gemm_sk(
    const float* __restrict__ A, const float* __restrict__ W,
    const float* __restrict__ bias, float* __restrict__ C,
    int N, int K, int kchunk, int ldc)
{
    int kbeg = blockIdx.y * kchunk;
    sk_body(A, K, W, bias, bias != nullptr && blockIdx.y == 0,
            C, ldc, N, kbeg, kbeg + kchunk, blockIdx.x * 64, blockIdx.z * 128);
}

// three h0 projections fused: weight/output selected by n-tile. grid (24,16)
__global__ __launch_bounds__(256) void hproj3_mfma(
    const float* __restrict__ h0,
    const float* __restrict__ Wa, const float* __restrict__ Wb, const float* __restrict__ Wc,
    float* __restrict__ hbase)
{
    int n0g = blockIdx.x * 64;
    int wsel = n0g >> 9;
    const float* W = (wsel == 0) ? Wa : (wsel == 1) ? Wb : Wc;
    float* C = hbase + (size_t)wsel * 128 * 512;
    int kbeg = blockIdx.y * 64;
    sk_body(h0, 1024, W, nullptr, 0, C, 512, 512, kbeg, kbeg + 64, n0g & 511, 0);
}

// both context projections fused into ctx[B,2,C]. grid (8,8,2)
__global__ __launch_bounds__(256) void ctxproj_mfma(
    const float* __restrict__ attv, const float* __restrict__ Wv,
    const float* __restrict__ atta, const float* __restrict__ Wa,
    float* __restrict__ ctx)
{
    const float* A; const float* W; float* C; int lda, kb, ke;
    if (blockIdx.z == 0) { A = attv; W = Wv; C = ctx;       lda = 1024; kb = blockIdx.y * 128; ke = kb + 128; }
    else                 { A = atta; W = Wa; C = ctx + 512; lda = 512;  kb = blockIdx.y * 64;  ke = kb + 64;  }
    sk_body(A, lda, W, nullptr, 0, C, 1024, 512, kb, ke, blockIdx.x * 64, 0);
}

// both LSTM gate GEMMs fused (biases applied in lstm_kernel). grid (64,16)
__global__ __launch_bounds__(256) void gates_mfma(
    const float* __restrict__ xb, const float* __restrict__ W_ih,
    const float* __restrict__ h0, const float* __restrict__ W_hh,
    float* __restrict__ gates)
{
    int pair = blockIdx.y >> 3;
    const float* A = pair ? h0 : xb;
    const float* W = pair ? W_hh : W_ih;
    int kb = (blockIdx.y & 7) * 128;
    sk_body(A, 1024, W, nullptr, 0, gates, 4096, 4096, kb, kb + 128, blockIdx.x * 64, 0);
}

// ===========================================================================
// Fused encoder-projection + attention-score kernel, BOTH modalities in one
// launch. Tile 64(M) x 128(N), BK=32, 256 thr (4 waves 2x2: 32m x 64n each).
// Prefetch depth 2, XOR-swizzled bf16 LDS double-buffer, non-draining
// barrier. A (enc) loads NON-TEMPORAL (streaming; protect W residency in
// the per-XCD L2 -- theory: W re-reads served from L3 at ~9TB/s are the
// 87us wall). W loads cacheable (reused by every m-block).
// Epilogue: p = sum_cols tanh(v1+v2)*W3, reduce 16 col-lanes, atomicAdd
// into sc[row]. N=512 exactly (4 n-tiles, no bounds checks).
// grid: 512 visual blocks (n*128+m) then 1024 audio blocks (512 + n*256+m).
// ===========================================================================
__global__ __launch_bounds__(256) void scores_fused(
    const float* __restrict__ encv, const float* __restrict__ W_va2,
    const float* __restrict__ hv1,  const float* __restrict__ W_va3,
    float* __restrict__ scv,
    const float* __restrict__ enca, const float* __restrict__ W_aa2,
    const float* __restrict__ ha1,  const float* __restrict__ W_aa3,
    float* __restrict__ sca)
{
    __shared__ short As[2][64 * 32];
    __shared__ short Ws[2][128 * 32];

    const float *A, *W, *v1, *W3;
    float* sc;
    int K, tshift, n0, m0;
    int idx = blockIdx.x;
    if (idx < 512) {            // visual: M=8192, K=1024, T=64
        n0 = (idx >> 7) * 128;  m0 = (idx & 127) * 64;
        A = encv; W = W_va2; v1 = hv1; W3 = W_va3; sc = scv;
        K = 1024; tshift = 6;
    } else {                    // audio: M=16384, K=512, T=128
        idx -= 512;
        n0 = (idx >> 8) * 128;  m0 = (idx & 255) * 64;
        A = enca; W = W_aa2; v1 = ha1; W3 = W_aa3; sc = sca;
        K = 512; tshift = 7;
    }

    const int tid  = threadIdx.x;
    const int lane = tid & 63;
    const int wave = tid >> 6;
    const int wm = (wave >> 1) * 32;
    const int wn = (wave & 1) * 64;

    f32x4 acc[2][4];
    #pragma unroll
    for (int i = 0; i < 2; ++i)
        #pragma unroll
        for (int j = 0; j < 4; ++j)
            acc[i][j] = (f32x4){0.f, 0.f, 0.f, 0.f};

    // A staging: row = tid>>2 (0..63), slot = tid&3
    const int arow  = tid >> 2;
    const int aslot = tid & 3;
    const float* gA = A + (size_t)(m0 + arow) * K + aslot * 8;
    const int aoff  = arow * 32 + ((aslot ^ ((arow >> 1) & 3)) * 8);

    // W staging: row = tid>>1 (0..127), k-half = tid&1 -> slots 2h, 2h+1
    const int wrow = tid >> 1;
    const int wh   = tid & 1;
    const int wfs  = (wrow >> 1) & 3;
    const float* gW = W + (size_t)(n0 + wrow) * K + wh * 16;
    const int woff0 = wrow * 32 + (((wh * 2)     ^ wfs) * 8);
    const int woff1 = wrow * 32 + (((wh * 2 + 1) ^ wfs) * 8);

    // fragment read offsets
    const int frow = lane & 15;
    const int hi   = lane >> 4;
    const int fsl  = (hi ^ ((frow >> 1) & 3)) * 8;
    const int ra   = (wm + frow) * 32 + fsl;
    const int rb   = (wn + frow) * 32 + fsl;

    const int nsteps = K >> 5;

    // prologue: K-tiles 0 and 1 into two register sets
    f32x4 a0_[2], a1_[2], w0_[4], w1_[4];
    a0_[0] = ldg_nt(gA);      a0_[1] = ldg_nt(gA + 4);
    a1_[0] = ldg_nt(gA + 32); a1_[1] = ldg_nt(gA + 36);
    #pragma unroll
    for (int q = 0; q < 4; ++q) w0_[q] = ldg(gW + q * 4);
    #pragma unroll
    for (int q = 0; q < 4; ++q) w1_[q] = ldg(gW + 32 + q * 4);

    for (int s = 0; s < nsteps; s += 2) {
        // ---- even step: consume set 0 into buf 0, reload set 0 from s+2 ----
        {
            short* as = As[0]; short* ws = Ws[0];
            *(short8*)(as + aoff)  = pack8(a0_[0], a0_[1]);
            *(short8*)(ws + woff0) = pack8(w0_[0], w0_[1]);
            *(short8*)(ws + woff1) = pack8(w0_[2], w0_[3]);
            if (s + 2 < nsteps) {
                const float* nA = gA + (s + 2) * 32;
                a0_[0] = ldg_nt(nA); a0_[1] = ldg_nt(nA + 4);
                const float* nW = gW + (s + 2) * 32;
                #pragma unroll
                for (int q = 0; q < 4; ++q) w0_[q] = ldg(nW + q * 4);
            }
            lds_barrier();
            short8 af[2], bf[4];
            #pragma unroll
            for (int i = 0; i < 2; ++i) af[i] = *(const short8*)(as + ra + i * 512);
            #pragma unroll
            for (int j = 0; j < 4; ++j) bf[j] = *(const short8*)(ws + rb + j * 512);
            #pragma unroll
            for (int i = 0; i < 2; ++i)
                #pragma unroll
                for (int j = 0; j < 4; ++j)
                    acc[i][j] = __builtin_amdgcn_mfma_f32_16x16x32_bf16(af[i], bf[j], acc[i][j], 0, 0, 0);
        }
        // ---- odd step: consume set 1 into buf 1, reload set 1 from s+3 ----
        {
            short* as = As[1]; short* ws = Ws[1];
            *(short8*)(as + aoff)  = pack8(a1_[0], a1_[1]);
            *(short8*)(ws + woff0) = pack8(w1_[0], w1_[1]);
            *(short8*)(ws + woff1) = pack8(w1_[2], w1_[3]);
            if (s + 3 < nsteps) {
                const float* nA = gA + (s + 3) * 32;
                a1_[0] = ldg_nt(nA); a1_[1] = ldg_nt(nA + 4);
                const float* nW = gW + (s + 3) * 32;
                #pragma unroll
                for (int q = 0; q < 4; ++q) w1_[q] = ldg(nW + q * 4);
            }
            lds_barrier();
            short8 af[2], bf[4];
            #pragma unroll
            for (int i = 0; i < 2; ++i) af[i] = *(const short8*)(as + ra + i * 512);
            #pragma unroll
            for (int j = 0; j < 4; ++j) bf[j] = *(const short8*)(ws + rb + j * 512);
            #pragma unroll
            for (int i = 0; i < 2; ++i)
                #pragma unroll
                for (int j = 0; j < 4; ++j)
                    acc[i][j] = __builtin_amdgcn_mfma_f32_16x16x32_bf16(af[i], bf[j], acc[i][j], 0, 0, 0);
        }
    }

    // epilogue: p = sum_cols tanh(v1[b,c] + v2) * W3[c]; reduce 16 col-lanes
    const int cl = lane & 15;
    const int rq = hi * 4;
    #pragma unroll
    for (int i = 0; i < 2; ++i) {
        #pragma unroll
        for (int r = 0; r < 4; ++r) {
            int gr = m0 + wm + i * 16 + rq + r;
            const float* v1row = v1 + (size_t)(gr >> tshift) * 512;
            float p = 0.f;
            #pragma unroll
            for (int j = 0; j < 4; ++j) {
                int gc = n0 + wn + j * 16 + cl;
                p += tanhf(v1row[gc] + acc[i][j][r]) * W3[gc];
            }
            p += __shfl_xor(p, 1, 64);
            p += __shfl_xor(p, 2, 64);
            p += __shfl_xor(p, 4, 64);
            p += __shfl_xor(p, 8, 64);
            if (cl == 0) atomicAdd(sc + gr, p);
        }
    }
}

// ===========================================================================
// Softmax over T + weighted sum, both modalities in one launch.
// grid (B, 6): y<4 -> visual e-chunk y; y>=4 -> audio e-chunk y-4.
// ===========================================================================
__global__ __launch_bounds__(256) void attend_out2(
    const float* __restrict__ scv, const float* __restrict__ encv, float* __restrict__ attv,
    const float* __restrict__ sca, const float* __restrict__ enca, float* __restrict__ atta)
{
    const float* sc; const float* enc; float* out;
    int T, E, ec;
    if (blockIdx.y < 4) { sc = scv; enc = encv; out = attv; T = 64;  E = 1024; ec = blockIdx.y; }
    else                { sc = sca; enc = enca; out = atta; T = 128; E = 512;  ec = blockIdx.y - 4; }

    __shared__ float ew[128];
    const int b = blockIdx.x, tid = threadIdx.x;
    __shared__ float raw[128];
    if (tid < T) raw[tid] = sc[(size_t)b * T + tid];
    __syncthreads();
    float m = -1e30f;
    for (int t = 0; t < T; ++t) m = fmaxf(m, raw[t]);
    if (tid < T) ew[tid] = __expf(raw[tid] - m);
    __syncthreads();
    float sum = 0.f;
    for (int t = 0; t < T; ++t) sum += ew[t];
    const float inv = 1.f / sum;

    const int e = ec * 256 + tid;
    const float* encb = enc + (size_t)b * T * E + e;
    float acc = 0.f;
    for (int t = 0; t < T; ++t)
        acc += ew[t] * encb[(size_t)t * E];
    out[(size_t)b * E + e] = acc * inv;
}

// ===========================================================================
// Cross-modal attention + build x = [input | tanh(final_ctx)]
// ===========================================================================
__global__ __launch_bounds__(256) void cross_kernel(
    const float* __restrict__ hc1, const float* __restrict__ v2c,
    const float* __restrict__ W3, const float* __restrict__ ctx,
    const float* __restrict__ inp, float* __restrict__ x)
{
    const int C = 512;
    __shared__ float red[256];
    __shared__ float aw[2];
    const int b = blockIdx.x, tid = threadIdx.x;

    float p0 = 0.f, p1 = 0.f;
    for (int c = tid; c < C; c += 256) {
        float h = hc1[(size_t)b * C + c], w = W3[c];
        p0 += tanhf(h + v2c[(size_t)(b * 2 + 0) * C + c]) * w;
        p1 += tanhf(h + v2c[(size_t)(b * 2 + 1) * C + c]) * w;
    }
    red[tid] = p0; __syncthreads();
    for (int s = 128; s; s >>= 1) { if (tid < s) red[tid] += red[tid + s]; __syncthreads(); }
    float s0 = red[0];
    __syncthreads();
    red[tid] = p1; __syncthreads();
    for (int s = 128; s; s >>= 1) { if (tid < s) red[tid] += red[tid + s]; __syncthreads(); }
    if (tid == 0) {
        float s1 = red[0];
        float m = fmaxf(s0, s1);
        float e0 = __expf(s0 - m), e1 = __expf(s1 - m);
        float inv = 1.f / (e0 + e1);
        aw[0] = e0 * inv; aw[1] = e1 * inv;
    }
    __syncthreads();
    float a0 = aw[0], a1 = aw[1];
    for (int c = tid; c < C; c += 256) {
        float fc = a0 * ctx[(size_t)(b * 2 + 0) * C + c]
                 + a1 * ctx[(size_t)(b * 2 + 1) * C + c];
        x[(size_t)b * 1024 + 512 + c] = tanhf(fc);
        x[(size_t)b * 1024 + c] = inp[(size_t)b * 512 + c];
    }
}

// ===========================================================================
// LSTM pointwise (biases folded in here)
// ===========================================================================
__global__ __launch_bounds__(256) void lstm_kernel(
    const float* __restrict__ gates, const float* __restrict__ c0,
    const float* __restrict__ b_ih, const float* __restrict__ b_hh,
    float* __restrict__ hout, float* __restrict__ cout)
{
    const int idx = blockIdx.x * 256 + threadIdx.x;   // B*H = 131072
    const int b = idx >> 10, h = idx & 1023;
    const float* g = gates + (size_t)b * 4096;
    float gi = g[h]        + b_ih[h]        + b_hh[h];
    float gf = g[1024 + h] + b_ih[1024 + h] + b_hh[1024 + h];
    float gg = g[2048 + h] + b_ih[2048 + h] + b_hh[2048 + h];
    float go = g[3072 + h] + b_ih[3072 + h] + b_hh[3072 + h];
    float si = 1.f / (1.f + __expf(-gi));
    float sf = 1.f / (1.f + __expf(-gf));
    float so = 1.f / (1.f + __expf(-go));
    float cn = sf * c0[idx] + si * tanhf(gg);
    float hn = so * tanhf(cn);
    cout[idx] = cn;
    hout[idx] = hn;
}

// ---------------------------------------------------------------------------
extern "C" void kernel_launch(void* const* d_in, const int* in_sizes, int n_in,
                              void* d_out, int out_size, void* d_ws, size_t ws_size,
                              hipStream_t stream)
{
    const float* inp    = (const float*)d_in[0];
    const float* encv   = (const float*)d_in[1];
    const float* enca   = (const float*)d_in[2];
    const float* h0     = (const float*)d_in[3];
    const float* c0     = (const float*)d_in[4];
    const float* W_va1  = (const float*)d_in[5];
    const float* W_va2  = (const float*)d_in[6];
    const float* W_va3  = (const float*)d_in[7];
    const float* W_venc = (const float*)d_in[8];
    const float* W_aa1  = (const float*)d_in[9];
    const float* W_aa2  = (const float*)d_in[10];
    const float* W_aa3  = (const float*)d_in[11];
    const float* W_aenc = (const float*)d_in[12];
    const float* W_ca1  = (const float*)d_in[13];
    const float* W_ca2  = (const float*)d_in[14];
    const float* W_ca3  = (const float*)d_in[15];
    const float* W_ih   = (const float*)d_in[16];
    const float* W_hh   = (const float*)d_in[17];
    const float* b_ih   = (const float*)d_in[18];
    const float* b_hh   = (const float*)d_in[19];
    const float* W_out  = (const float*)d_in[20];
    const float* b_out  = (const float*)d_in[21];
    float* out = (float*)d_out;

    // workspace layout: [zero-initialized region | plain scratch]
    float* ws = (float*)d_ws;
    float* hv1  = ws;  ws += 128 * 512;                 // zeroed (atomic targets)
    float* ha1  = ws;  ws += 128 * 512;
    float* hc1  = ws;  ws += 128 * 512;
    float* scv  = ws;  ws += 128 * 64;
    float* sca  = ws;  ws += 128 * 128;
    float* ctx  = ws;  ws += 128 * 2 * 512;
    float* v2c  = ws;  ws += 128 * 2 * 512;
    float* gates= ws;  ws += (size_t)128 * 4096;
    size_t zero_floats = (size_t)(ws - (float*)d_ws);
    float* xb   = ws;  ws += 128 * 1024;
    float* attv = ws;  ws += 128 * 1024;
    float* atta = ws;  ws += 128 * 512;

    dim3 blk(256);

    // 0. zero all atomic-accumulation targets + the logits output region
    hipMemsetAsync(d_ws, 0, zero_floats * sizeof(float), stream);
    hipMemsetAsync(out, 0, (size_t)128 * 20000 * sizeof(float), stream);

    // 1. three h0 projections, one MFMA launch: grid (24, 16) = 384 blocks
    hproj3_mfma<<<dim3(24, 16), blk, 0, stream>>>(h0, W_va1, W_aa1, W_ca1, hv1);
    // 2. both encoder projections + fused tanh-scores: 1536 blocks, one launch
    scores_fused<<<dim3(1536), blk, 0, stream>>>(encv, W_va2, hv1, W_va3, scv,
                                                 enca, W_aa2, ha1, W_aa3, sca);
    // 3. softmax + weighted encoder sum, both modalities: grid (128, 6)
    attend_out2<<<dim3(128, 6), blk, 0, stream>>>(scv, encv, attv, sca, enca, atta);
    // 4. both context projections -> ctx[B,2,C]: grid (8,8,2) = 128 blocks
    ctxproj_mfma<<<dim3(8, 8, 2), blk, 0, stream>>>(attv, W_venc, atta, W_aenc, ctx);
    // 5. cross-modal key projection: split-K 8 -> 128 blocks
    gemm_sk<<<dim3(8, 8, 2), blk, 0, stream>>>(ctx, W_ca2, nullptr, v2c, 512, 512, 64, 512);
    // 6. cross-modal attention + x build
    cross_kernel<<<128, blk, 0, stream>>>(hc1, v2c, W_ca3, ctx, inp, xb);
    // 7. LSTM gates: both GEMMs, split-K 8 each: grid (64, 16) = 1024 blocks
    gates_mfma<<<dim3(64, 16), blk, 0, stream>>>(xb, W_ih, h0, W_hh, gates);
    // 8. LSTM pointwise (+biases) -> h_new, c_new in d_out tail
    float* hout = out + 2560000;
    float* cout = out + 2560000 + 131072;
    lstm_kernel<<<512, blk, 0, stream>>>(gates, c0, b_ih, b_hh, hout, cout);
    // 9. logits: split-K 4, bias added by chunk 0. grid (313, 4) = 1252 blocks
    gemm_sk<<<dim3(313, 4, 1), blk, 0, stream>>>(hout, W_out, b_out, out, 20000, 1024, 256, 20000);
}

// Round 6
// 374.575 us; speedup vs baseline: 1.1144x; 1.1144x over previous
//
#include <hip/hip_runtime.h>
#include <hip/hip_bf16.h>
#include <cstddef>

typedef __attribute__((ext_vector_type(8))) short short8;   // 8 bf16 = 4 VGPR
typedef __attribute__((ext_vector_type(4))) float f32x4;

// cacheable 16B load
static __device__ __forceinline__ f32x4 ldg(const float* p) {
    return *(const f32x4*)p;
}

static __device__ __forceinline__ short8 pack8(f32x4 f0, f32x4 f1) {
    union { __hip_bfloat162 h[4]; short8 s; } u;
    u.h[0] = __float22bfloat162_rn(make_float2(f0.x, f0.y));
    u.h[1] = __float22bfloat162_rn(make_float2(f0.z, f0.w));
    u.h[2] = __float22bfloat162_rn(make_float2(f1.x, f1.y));
    u.h[3] = __float22bfloat162_rn(make_float2(f1.z, f1.w));
    return u.s;
}

// async global->LDS, 16B per lane (emits global_load_lds_dwordx4)
static __device__ __forceinline__ void gload16(const short* g, short* l) {
    __builtin_amdgcn_global_load_lds(
        (const __attribute__((address_space(1))) void*)g,
        (__attribute__((address_space(3))) void*)l, 16, 0, 0);
}

// Non-draining workgroup barrier (lgkmcnt only; prefetch loads stay in flight).
static __device__ __forceinline__ void lds_barrier() {
    asm volatile("s_waitcnt lgkmcnt(0)" ::: "memory");
    __builtin_amdgcn_s_barrier();
    asm volatile("" ::: "memory");
}

// ===========================================================================
// Generic split-K bf16 MFMA body (f32 inputs, reg-staged): adds
// A[m0:m0+128, kbeg:kend] @ W^T tile into C via atomicAdd. Tile 128x64,
// BK=32, 256 thr. Prefetch depth 2, XOR-swizzled bf16 LDS double-buffer
// (0 conflicts measured), ONE non-draining barrier per K-step.
// Requires nsteps even and >= 2 (all call sites satisfy this).
// ===========================================================================
static __device__ __forceinline__ void sk_body(
    const float* __restrict__ A, int lda,
    const float* __restrict__ W,
    const float* __restrict__ bias, int addbias,
    float* __restrict__ C, int ldc, int N,
    int kbeg, int kend, int n0, int m0)
{
    __shared__ short As[2][128 * 32];
    __shared__ short Ws[2][64 * 32];
    const int tid  = threadIdx.x;
    const int lane = tid & 63;
    const int wave = tid >> 6;
    const int wm = wave * 32;

    f32x4 acc[2][4];
    #pragma unroll
    for (int i = 0; i < 2; ++i)
        #pragma unroll
        for (int j = 0; j < 4; ++j)
            acc[i][j] = (f32x4){0.f, 0.f, 0.f, 0.f};

    // A staging: row = tid>>1 (0..127), k-half = tid&1 -> slots 2h, 2h+1
    const int arow = tid >> 1;
    const int ah   = tid & 1;
    const int afs  = (arow >> 1) & 3;
    const float* gA = A + (size_t)(m0 + arow) * lda + kbeg + ah * 16;
    const int aoff0 = arow * 32 + (((ah * 2)     ^ afs) * 8);
    const int aoff1 = arow * 32 + (((ah * 2 + 1) ^ afs) * 8);

    // W staging: row = tid>>2 (0..63), slot = tid&3
    const int wrow  = tid >> 2;
    const int wslot = tid & 3;
    const int wvalid = (n0 + wrow) < N;
    const float* gW = W + (size_t)(n0 + wrow) * lda + kbeg + wslot * 8;
    const int woff = wrow * 32 + ((wslot ^ ((wrow >> 1) & 3)) * 8);

    // fragment read offsets
    const int frow = lane & 15;
    const int hi   = lane >> 4;
    const int fsl  = (hi ^ ((frow >> 1) & 3)) * 8;
    const int ra   = (wm + frow) * 32 + fsl;
    const int rb   = frow * 32 + fsl;

    const int nsteps = (kend - kbeg) >> 5;

    // prologue: K-tiles 0 and 1 into two register sets
    f32x4 a0_[4], a1_[4], w0_[2], w1_[2];
    #pragma unroll
    for (int q = 0; q < 4; ++q) a0_[q] = ldg(gA + q * 4);
    #pragma unroll
    for (int q = 0; q < 4; ++q) a1_[q] = ldg(gA + 32 + q * 4);
    if (wvalid) {
        w0_[0] = ldg(gW);      w0_[1] = ldg(gW + 4);
        w1_[0] = ldg(gW + 32); w1_[1] = ldg(gW + 36);
    } else {
        w0_[0] = w0_[1] = w1_[0] = w1_[1] = (f32x4){0.f, 0.f, 0.f, 0.f};
    }

    for (int s = 0; s < nsteps; s += 2) {
        // ---- even step: consume set 0 into buf 0, reload set 0 from s+2 ----
        {
            short* as = As[0]; short* ws = Ws[0];
            *(short8*)(as + aoff0) = pack8(a0_[0], a0_[1]);
            *(short8*)(as + aoff1) = pack8(a0_[2], a0_[3]);
            *(short8*)(ws + woff)  = pack8(w0_[0], w0_[1]);
            if (s + 2 < nsteps) {
                const float* nA = gA + (s + 2) * 32;
                #pragma unroll
                for (int q = 0; q < 4; ++q) a0_[q] = ldg(nA + q * 4);
                if (wvalid) {
                    const float* nW = gW + (s + 2) * 32;
                    w0_[0] = ldg(nW); w0_[1] = ldg(nW + 4);
                }
            }
            lds_barrier();
            short8 af[2], bf[4];
            #pragma unroll
            for (int i = 0; i < 2; ++i) af[i] = *(const short8*)(as + ra + i * 512);
            #pragma unroll
            for (int j = 0; j < 4; ++j) bf[j] = *(const short8*)(ws + rb + j * 512);
            #pragma unroll
            for (int i = 0; i < 2; ++i)
                #pragma unroll
                for (int j = 0; j < 4; ++j)
                    acc[i][j] = __builtin_amdgcn_mfma_f32_16x16x32_bf16(af[i], bf[j], acc[i][j], 0, 0, 0);
        }
        // ---- odd step: consume set 1 into buf 1, reload set 1 from s+3 ----
        {
            short* as = As[1]; short* ws = Ws[1];
            *(short8*)(as + aoff0) = pack8(a1_[0], a1_[1]);
            *(short8*)(as + aoff1) = pack8(a1_[2], a1_[3]);
            *(short8*)(ws + woff)  = pack8(w1_[0], w1_[1]);
            if (s + 3 < nsteps) {
                const float* nA = gA + (s + 3) * 32;
                #pragma unroll
                for (int q = 0; q < 4; ++q) a1_[q] = ldg(nA + q * 4);
                if (wvalid) {
                    const float* nW = gW + (s + 3) * 32;
                    w1_[0] = ldg(nW); w1_[1] = ldg(nW + 4);
                }
            }
            lds_barrier();
            short8 af[2], bf[4];
            #pragma unroll
            for (int i = 0; i < 2; ++i) af[i] = *(const short8*)(as + ra + i * 512);
            #pragma unroll
            for (int j = 0; j < 4; ++j) bf[j] = *(const short8*)(ws + rb + j * 512);
            #pragma unroll
            for (int i = 0; i < 2; ++i)
                #pragma unroll
                for (int j = 0; j < 4; ++j)
                    acc[i][j] = __builtin_amdgcn_mfma_f32_16x16x32_bf16(af[i], bf[j], acc[i][j], 0, 0, 0);
        }
    }

    const int cl = lane & 15;
    const int rq = hi * 4;
    #pragma unroll
    for (int j = 0; j < 4; ++j) {
        int gc = n0 + j * 16 + cl;
        if (gc >= N) continue;
        float b = addbias ? bias[gc] : 0.f;
        #pragma unroll
        for (int i = 0; i < 2; ++i) {
            int gr = m0 + wm + i * 16 + rq;
            #pragma unroll
            for (int r = 0; r < 4; ++r)
                atomicAdd(C + (size_t)(gr + r) * ldc + gc, acc[i][j][r] + b);
        }
    }
}

// generic wrapper: grid (ceil(N/64), ksplit, M/128)
__global__ __launch_bounds__(256) void gemm_sk(
    const float* __restrict__ A, const float* __restrict__ W,
    const float* __restrict__ bias, float* __restrict__ C,
    int N, int K, int kchunk, int ldc)
{
    int kbeg = blockIdx.y * kchunk;
    sk_body(A, K, W, bias, bias != nullptr && blockIdx.y == 0,
            C, ldc, N, kbeg, kbeg + kchunk, blockIdx.x * 64, blockIdx.z * 128);
}

// three h0 projections fused: weight/output selected by n-tile. grid (24,8)
__global__ __launch_bounds__(256) void hproj3_mfma(
    const float* __restrict__ h0,
    const float* __restrict__ Wa, const float* __restrict__ Wb, const float* __restrict__ Wc,
    float* __restrict__ hbase)
{
    int n0g = blockIdx.x * 64;
    int wsel = n0g >> 9;
    const float* W = (wsel == 0) ? Wa : (wsel == 1) ? Wb : Wc;
    float* C = hbase + (size_t)wsel * 128 * 512;
    int kbeg = blockIdx.y * 128;
    sk_body(h0, 1024, W, nullptr, 0, C, 512, 512, kbeg, kbeg + 128, n0g & 511, 0);
}

// both context projections fused into ctx[B,2,C]. grid (8,8,2)
__global__ __launch_bounds__(256) void ctxproj_mfma(
    const float* __restrict__ attv, const float* __restrict__ Wv,
    const float* __restrict__ atta, const float* __restrict__ Wa,
    float* __restrict__ ctx)
{
    const float* A; const float* W; float* C; int lda, kb, ke;
    if (blockIdx.z == 0) { A = attv; W = Wv; C = ctx;       lda = 1024; kb = blockIdx.y * 128; ke = kb + 128; }
    else                 { A = atta; W = Wa; C = ctx + 512; lda = 512;  kb = blockIdx.y * 64;  ke = kb + 64;  }
    sk_body(A, lda, W, nullptr, 0, C, 1024, 512, kb, ke, blockIdx.x * 64, 0);
}

// both LSTM gate GEMMs fused (biases applied in lstm_kernel). grid (64,8)
__global__ __launch_bounds__(256) void gates_mfma(
    const float* __restrict__ xb, const float* __restrict__ W_ih,
    const float* __restrict__ h0, const float* __restrict__ W_hh,
    float* __restrict__ gates)
{
    int pair = blockIdx.y >> 2;
    const float* A = pair ? h0 : xb;
    const float* W = pair ? W_hh : W_ih;
    int kb = (blockIdx.y & 3) * 256;
    sk_body(A, 1024, W, nullptr, 0, gates, 4096, 4096, kb, kb + 256, blockIdx.x * 64, 0);
}

// ===========================================================================
// bf16 pre-conversion of enc_visual, enc_audio, W_va2, W_aa2.
// grid 8576 x 256, 8 elems/thread (32B read, 16B write). ~105MB traffic.
// Enables global_load_lds direct staging in scores_fused (no VALU pack).
// ===========================================================================
__global__ __launch_bounds__(256) void cvt_bf16(
    const float* __restrict__ encv, const float* __restrict__ enca,
    const float* __restrict__ wv2,  const float* __restrict__ wa2,
    short* __restrict__ oev, short* __restrict__ oea,
    short* __restrict__ owv, short* __restrict__ owa)
{
    int bid = blockIdx.x;
    const float* src; short* dst; int lb;
    if (bid < 4096)      { src = encv; dst = oev; lb = bid; }        // 8.39M elems
    else if (bid < 8192) { src = enca; dst = oea; lb = bid - 4096; } // 8.39M
    else if (bid < 8448) { src = wv2;  dst = owv; lb = bid - 8192; } // 524288
    else                 { src = wa2;  dst = owa; lb = bid - 8448; } // 262144
    size_t off = ((size_t)lb * 256 + threadIdx.x) * 8;
    f32x4 f0 = *(const f32x4*)(src + off);
    f32x4 f1 = *(const f32x4*)(src + off + 4);
    *(short8*)(dst + off) = pack8(f0, f1);
}

// ===========================================================================
// Fused encoder-projection + attention-score kernel, m97 structure:
// bf16 inputs, 128(M) x 128(N) tile, BK=32, 256 thr (4 waves 2x2, each
// 64x64 = 16 MFMA/K-step), staging via global_load_lds width=16 (zero
// staging VALU/registers), counted s_waitcnt vmcnt(4) -- never drained in
// the main loop. LDS linear in lane order (gload_lds requirement); the
// r2-verified XOR swizzle (0 conflicts) is applied by PRE-SWIZZLING the
// global source and swizzling the ds_read address (rule #21: same
// involution both sides, LDS itself stays linear).
// Epilogue: p = sum_cols tanh(v1+v2)*W3, reduce 16 col-lanes, atomicAdd
// into sc[row]. N=512 exactly (4 n-tiles, no bounds checks).
// Block order n-major; m-tiles per modality % 8 == 0 -> XCD-friendly.
// grid: 256 visual blocks (n*64+m) then 512 audio blocks (256 + n*128+m).
// ===========================================================================
__global__ __launch_bounds__(256) void scores_fused(
    const short* __restrict__ Av, const short* __restrict__ Wv,
    const float* __restrict__ hv1,  const float* __restrict__ W_va3,
    float* __restrict__ scv,
    const short* __restrict__ Aa, const short* __restrict__ Wa,
    const float* __restrict__ ha1,  const float* __restrict__ W_aa3,
    float* __restrict__ sca)
{
    __shared__ short As[2][4096];   // 128 rows x 32 bf16, double-buffered
    __shared__ short Ws[2][4096];

    const short *A, *W; const float *v1, *W3;
    float* sc;
    int K, tshift, n0, m0;
    int idx = blockIdx.x;
    if (idx < 256) {            // visual: M=8192, K=1024, T=64 -> 64 mtiles
        n0 = (idx >> 6) * 128;  m0 = (idx & 63) * 128;
        A = Av; W = Wv; v1 = hv1; W3 = W_va3; sc = scv;
        K = 1024; tshift = 6;
    } else {                    // audio: M=16384, K=512, T=128 -> 128 mtiles
        idx -= 256;
        n0 = (idx >> 7) * 128;  m0 = (idx & 127) * 128;
        A = Aa; W = Wa; v1 = ha1; W3 = W_aa3; sc = sca;
        K = 512; tshift = 7;
    }

    const int tid  = threadIdx.x;
    const int lane = tid & 63;
    const int wave = tid >> 6;
    const int wr = wave >> 1;          // 0..1 : 64-row half
    const int wc = wave & 1;           // 0..1 : 64-col half

    f32x4 acc[4][4];
    #pragma unroll
    for (int i = 0; i < 4; ++i)
        #pragma unroll
        for (int j = 0; j < 4; ++j)
            acc[i][j] = (f32x4){0.f, 0.f, 0.f, 0.f};

    // --- staging: wave w lanes cover rows 16w..16w+15 (4 lanes/row, 16B each)
    // pre-swizzled source slot: phys slot (lane&3) holds logical (lane&3)^fs,
    // fs = (row>>1)&3 = (lane>>3)&3 (wave*16 contributes 0 mod 4 after >>1)
    const int srow = lane >> 2;                       // 0..15
    const int slsw = (lane & 3) ^ ((lane >> 3) & 3);  // pre-swizzled k-slot
    const short* gA0 = A + (size_t)(m0 + wave * 16 + srow) * K + slsw * 8;
    const short* gA1 = gA0 + (size_t)64 * K;
    const short* gW0 = W + (size_t)(n0 + wave * 16 + srow) * K + slsw * 8;
    const short* gW1 = gW0 + (size_t)64 * K;
    const int ldsw = wave * 512;       // wave-uniform LDS base (shorts)

    // --- fragment read offsets (swizzled read, verified 0-conflict in r2)
    const int frow = lane & 15;
    const int hi   = lane >> 4;
    const int fsl  = (hi ^ ((frow >> 1) & 3)) * 8;
    const int raBase = (wr * 64 + frow) * 32 + fsl;
    const int rbBase = (wc * 64 + frow) * 32 + fsl;

    const int nsteps = K >> 5;

    // prologue: stage K-tile 0 into buffer 0 (4 issues -> vmcnt 4)
    gload16(gA0, As[0] + ldsw);
    gload16(gA1, As[0] + 2048 + ldsw);
    gload16(gW0, Ws[0] + ldsw);
    gload16(gW1, Ws[0] + 2048 + ldsw);

    int cur = 0;
    for (int s = 0; s < nsteps; ++s) {
        // issue next tile into the other buffer (last iter: redundant re-load
        // of the current tile -- never read, keeps vmcnt accounting uniform)
        int nk = (s + 1 < nsteps ? s + 1 : s) * 32;
        gload16(gA0 + nk, As[cur ^ 1] + ldsw);
        gload16(gA1 + nk, As[cur ^ 1] + 2048 + ldsw);
        gload16(gW0 + nk, Ws[cur ^ 1] + ldsw);
        gload16(gW1 + nk, Ws[cur ^ 1] + 2048 + ldsw);
        // wait for CURRENT tile only; next tile's 4 loads stay in flight
        asm volatile("s_waitcnt vmcnt(4)" ::: "memory");
        __builtin_amdgcn_s_barrier();
        __builtin_amdgcn_sched_barrier(0);   // pin ds_reads below the barrier

        const short* as = As[cur];
        const short* ws = Ws[cur];
        short8 af[4], bf[4];
        #pragma unroll
        for (int i = 0; i < 4; ++i) af[i] = *(const short8*)(as + raBase + i * 512);
        #pragma unroll
        for (int j = 0; j < 4; ++j) bf[j] = *(const short8*)(ws + rbBase + j * 512);
        #pragma unroll
        for (int i = 0; i < 4; ++i)
            #pragma unroll
            for (int j = 0; j < 4; ++j)
                acc[i][j] = __builtin_amdgcn_mfma_f32_16x16x32_bf16(af[i], bf[j], acc[i][j], 0, 0, 0);
        __builtin_amdgcn_sched_barrier(0);
        __builtin_amdgcn_s_barrier();        // reads of buf cur done -> next
        cur ^= 1;                            // iter may overwrite it
    }

    // epilogue: p = sum_cols tanh(v1[b,c] + v2) * W3[c]; reduce 16 col-lanes
    const int cl = lane & 15;
    const int rq = hi * 4;
    #pragma unroll
    for (int i = 0; i < 4; ++i) {
        #pragma unroll
        for (int r = 0; r < 4; ++r) {
            int gr = m0 + wr * 64 + i * 16 + rq + r;
            const float* v1row = v1 + (size_t)(gr >> tshift) * 512;
            float p = 0.f;
            #pragma unroll
            for (int j = 0; j < 4; ++j) {
                int gc = n0 + wc * 64 + j * 16 + cl;
                p += tanhf(v1row[gc] + acc[i][j][r]) * W3[gc];
            }
            p += __shfl_xor(p, 1, 64);
            p += __shfl_xor(p, 2, 64);
            p += __shfl_xor(p, 4, 64);
            p += __shfl_xor(p, 8, 64);
            if (cl == 0) atomicAdd(sc + gr, p);
        }
    }
}

// ===========================================================================
// Softmax over T + weighted sum, both modalities in one launch.
// grid (B, 6): y<4 -> visual e-chunk y; y>=4 -> audio e-chunk y-4.
// ===========================================================================
__global__ __launch_bounds__(256) void attend_out2(
    const float* __restrict__ scv, const float* __restrict__ encv, float* __restrict__ attv,
    const float* __restrict__ sca, const float* __restrict__ enca, float* __restrict__ atta)
{
    const float* sc; const float* enc; float* out;
    int T, E, ec;
    if (blockIdx.y < 4) { sc = scv; enc = encv; out = attv; T = 64;  E = 1024; ec = blockIdx.y; }
    else                { sc = sca; enc = enca; out = atta; T = 128; E = 512;  ec = blockIdx.y - 4; }

    __shared__ float ew[128];
    const int b = blockIdx.x, tid = threadIdx.x;
    __shared__ float raw[128];
    if (tid < T) raw[tid] = sc[(size_t)b * T + tid];
    __syncthreads();
    float m = -1e30f;
    for (int t = 0; t < T; ++t) m = fmaxf(m, raw[t]);
    if (tid < T) ew[tid] = __expf(raw[tid] - m);
    __syncthreads();
    float sum = 0.f;
    for (int t = 0; t < T; ++t) sum += ew[t];
    const float inv = 1.f / sum;

    const int e = ec * 256 + tid;
    const float* encb = enc + (size_t)b * T * E + e;
    float acc = 0.f;
    for (int t = 0; t < T; ++t)
        acc += ew[t] * encb[(size_t)t * E];
    out[(size_t)b * E + e] = acc * inv;
}

// ===========================================================================
// Cross-modal attention + build x = [input | tanh(final_ctx)]
// ===========================================================================
__global__ __launch_bounds__(256) void cross_kernel(
    const float* __restrict__ hc1, const float* __restrict__ v2c,
    const float* __restrict__ W3, const float* __restrict__ ctx,
    const float* __restrict__ inp, float* __restrict__ x)
{
    const int C = 512;
    __shared__ float red[256];
    __shared__ float aw[2];
    const int b = blockIdx.x, tid = threadIdx.x;

    float p0 = 0.f, p1 = 0.f;
    for (int c = tid; c < C; c += 256) {
        float h = hc1[(size_t)b * C + c], w = W3[c];
        p0 += tanhf(h + v2c[(size_t)(b * 2 + 0) * C + c]) * w;
        p1 += tanhf(h + v2c[(size_t)(b * 2 + 1) * C + c]) * w;
    }
    red[tid] = p0; __syncthreads();
    for (int s = 128; s; s >>= 1) { if (tid < s) red[tid] += red[tid + s]; __syncthreads(); }
    float s0 = red[0];
    __syncthreads();
    red[tid] = p1; __syncthreads();
    for (int s = 128; s; s >>= 1) { if (tid < s) red[tid] += red[tid + s]; __syncthreads(); }
    if (tid == 0) {
        float s1 = red[0];
        float m = fmaxf(s0, s1);
        float e0 = __expf(s0 - m), e1 = __expf(s1 - m);
        float inv = 1.f / (e0 + e1);
        aw[0] = e0 * inv; aw[1] = e1 * inv;
    }
    __syncthreads();
    float a0 = aw[0], a1 = aw[1];
    for (int c = tid; c < C; c += 256) {
        float fc = a0 * ctx[(size_t)(b * 2 + 0) * C + c]
                 + a1 * ctx[(size_t)(b * 2 + 1) * C + c];
        x[(size_t)b * 1024 + 512 + c] = tanhf(fc);
        x[(size_t)b * 1024 + c] = inp[(size_t)b * 512 + c];
    }
}

// ===========================================================================
// LSTM pointwise (biases folded in here)
// ===========================================================================
__global__ __launch_bounds__(256) void lstm_kernel(
    const float* __restrict__ gates, const float* __restrict__ c0,
    const float* __restrict__ b_ih, const float* __restrict__ b_hh,
    float* __restrict__ hout, float* __restrict__ cout)
{
    const int idx = blockIdx.x * 256 + threadIdx.x;   // B*H = 131072
    const int b = idx >> 10, h = idx & 1023;
    const float* g = gates + (size_t)b * 4096;
    float gi = g[h]        + b_ih[h]        + b_hh[h];
    float gf = g[1024 + h] + b_ih[1024 + h] + b_hh[1024 + h];
    float gg = g[2048 + h] + b_ih[2048 + h] + b_hh[2048 + h];
    float go = g[3072 + h] + b_ih[3072 + h] + b_hh[3072 + h];
    float si = 1.f / (1.f + __expf(-gi));
    float sf = 1.f / (1.f + __expf(-gf));
    float so = 1.f / (1.f + __expf(-go));
    float cn = sf * c0[idx] + si * tanhf(gg);
    float hn = so * tanhf(cn);
    cout[idx] = cn;
    hout[idx] = hn;
}

// ---------------------------------------------------------------------------
extern "C" void kernel_launch(void* const* d_in, const int* in_sizes, int n_in,
                              void* d_out, int out_size, void* d_ws, size_t ws_size,
                              hipStream_t stream)
{
    const float* inp    = (const float*)d_in[0];
    const float* encv   = (const float*)d_in[1];
    const float* enca   = (const float*)d_in[2];
    const float* h0     = (const float*)d_in[3];
    const float* c0     = (const float*)d_in[4];
    const float* W_va1  = (const float*)d_in[5];
    const float* W_va2  = (const float*)d_in[6];
    const float* W_va3  = (const float*)d_in[7];
    const float* W_venc = (const float*)d_in[8];
    const float* W_aa1  = (const float*)d_in[9];
    const float* W_aa2  = (const float*)d_in[10];
    const float* W_aa3  = (const float*)d_in[11];
    const float* W_aenc = (const float*)d_in[12];
    const float* W_ca1  = (const float*)d_in[13];
    const float* W_ca2  = (const float*)d_in[14];
    const float* W_ca3  = (const float*)d_in[15];
    const float* W_ih   = (const float*)d_in[16];
    const float* W_hh   = (const float*)d_in[17];
    const float* b_ih   = (const float*)d_in[18];
    const float* b_hh   = (const float*)d_in[19];
    const float* W_out  = (const float*)d_in[20];
    const float* b_out  = (const float*)d_in[21];
    float* out = (float*)d_out;

    // workspace layout: [zero-initialized region | plain scratch | bf16 copies]
    float* ws = (float*)d_ws;
    float* hv1  = ws;  ws += 128 * 512;                 // zeroed (atomic targets)
    float* ha1  = ws;  ws += 128 * 512;
    float* hc1  = ws;  ws += 128 * 512;
    float* scv  = ws;  ws += 128 * 64;
    float* sca  = ws;  ws += 128 * 128;
    float* ctx  = ws;  ws += 128 * 2 * 512;
    float* v2c  = ws;  ws += 128 * 2 * 512;
    float* gates= ws;  ws += (size_t)128 * 4096;
    size_t zero_floats = (size_t)(ws - (float*)d_ws);
    float* xb   = ws;  ws += 128 * 1024;
    float* attv = ws;  ws += 128 * 1024;
    float* atta = ws;  ws += 128 * 512;
    short* encv_bf = (short*)ws;  ws += 8388608 / 2;    // 128*64*1024 bf16
    short* enca_bf = (short*)ws;  ws += 8388608 / 2;    // 128*128*512 bf16
    short* wv2_bf  = (short*)ws;  ws += 524288 / 2;     // 512*1024 bf16
    short* wa2_bf  = (short*)ws;  ws += 262144 / 2;     // 512*512 bf16

    dim3 blk(256);

    // 0. zero all atomic-accumulation targets + the logits output region
    hipMemsetAsync(d_ws, 0, zero_floats * sizeof(float), stream);
    hipMemsetAsync(out, 0, (size_t)128 * 20000 * sizeof(float), stream);

    // 1. bf16 pre-conversion of enc + score weights: 8576 blocks
    cvt_bf16<<<dim3(8576), blk, 0, stream>>>(encv, enca, W_va2, W_aa2,
                                             encv_bf, enca_bf, wv2_bf, wa2_bf);
    // 2. three h0 projections, one MFMA launch: grid (24, 8) = 192 blocks
    hproj3_mfma<<<dim3(24, 8), blk, 0, stream>>>(h0, W_va1, W_aa1, W_ca1, hv1);
    // 3. encoder projections + fused tanh-scores, m97 structure: 768 blocks
    scores_fused<<<dim3(768), blk, 0, stream>>>(encv_bf, wv2_bf, hv1, W_va3, scv,
                                                enca_bf, wa2_bf, ha1, W_aa3, sca);
    // 4. softmax + weighted encoder sum, both modalities: grid (128, 6)
    attend_out2<<<dim3(128, 6), blk, 0, stream>>>(scv, encv, attv, sca, enca, atta);
    // 5. both context projections -> ctx[B,2,C]: grid (8,8,2) = 128 blocks
    ctxproj_mfma<<<dim3(8, 8, 2), blk, 0, stream>>>(attv, W_venc, atta, W_aenc, ctx);
    // 6. cross-modal key projection: split-K 4 -> 128 blocks
    gemm_sk<<<dim3(8, 4, 2), blk, 0, stream>>>(ctx, W_ca2, nullptr, v2c, 512, 512, 128, 512);
    // 7. cross-modal attention + x build
    cross_kernel<<<128, blk, 0, stream>>>(hc1, v2c, W_ca3, ctx, inp, xb);
    // 8. LSTM gates: both GEMMs, split-K 4 each: grid (64, 8) = 512 blocks
    gates_mfma<<<dim3(64, 8), blk, 0, stream>>>(xb, W_ih, h0, W_hh, gates);
    // 9. LSTM pointwise (+biases) -> h_new, c_new in d_out tail
    float* hout = out + 2560000;
    float* cout = out + 2560000 + 131072;
    lstm_kernel<<<512, blk, 0, stream>>>(gates, c0, b_ih, b_hh, hout, cout);
    // 10. logits: split-K 2, bias added by chunk 0. grid (313, 2) = 626 blocks
    gemm_sk<<<dim3(313, 2, 1), blk, 0, stream>>>(hout, W_out, b_out, out, 20000, 1024, 512, 20000);
}